// Round 1
// 546.148 us; speedup vs baseline: 1.0080x; 1.0080x over previous
//
#include <hip/hip_runtime.h>
#include <cmath>

#define C_DIM 128
#define S_DIM 4096
#define HW    176     // 16*11 floats per frame-row
#define HW4   44      // float4 per row
#define B_SEG 32
#define O_DIM 256

// ---------------- Kernel 1: ragged segment max over S (v3) ----------------
// grid = B_SEG*C_DIM = 4096 blocks, block = 704 threads = 11 full waves.
// Flat-float4 decomposition of the contiguous slab x[(c*S+s0)*176 ...]:
// thread t owns float4-position pos = t%44 (fixed) and row residue rg = t/44
// (mod 16). All 64 lanes of every wave issue 16B loads (11264 B contiguous
// per block step), 4 rows deep in flight. 16-way LDS max-reduce at the end.
__global__ __launch_bounds__(704) void seg_max_kernel(
    const float* __restrict__ x, const int* __restrict__ seqL,
    float* __restrict__ pooled)
{
    int bc = blockIdx.x;
    int c  = bc & (C_DIM - 1);
    int b  = bc >> 7;

    __shared__ int sL[B_SEG];
    __shared__ __align__(16) float red[16 * HW];   // 11.0 KB

    int t = threadIdx.x;
    if (t < B_SEG) sL[t] = seqL[t];
    __syncthreads();

    int s0 = 0;
    for (int i = 0; i < b; ++i) s0 += sL[i];
    int len = sL[b];

    unsigned pos = (unsigned)t % 44u;   // float4 position within row
    unsigned rg  = (unsigned)t / 44u;   // row residue class 0..15

    const float4* xp = (const float4*)(x + ((size_t)c * S_DIM + s0) * HW);

    float4 m = make_float4(-INFINITY, -INFINITY, -INFINITY, -INFINITY);

    int r = (int)rg;
    // 4 rows (stride 16) in flight per thread
    for (; r + 48 < len; r += 64) {
        float4 a0 = xp[(size_t)(r     ) * HW4 + pos];
        float4 a1 = xp[(size_t)(r + 16) * HW4 + pos];
        float4 a2 = xp[(size_t)(r + 32) * HW4 + pos];
        float4 a3 = xp[(size_t)(r + 48) * HW4 + pos];
        m.x = fmaxf(m.x, fmaxf(fmaxf(a0.x, a1.x), fmaxf(a2.x, a3.x)));
        m.y = fmaxf(m.y, fmaxf(fmaxf(a0.y, a1.y), fmaxf(a2.y, a3.y)));
        m.z = fmaxf(m.z, fmaxf(fmaxf(a0.z, a1.z), fmaxf(a2.z, a3.z)));
        m.w = fmaxf(m.w, fmaxf(fmaxf(a0.w, a1.w), fmaxf(a2.w, a3.w)));
    }
    for (; r < len; r += 16) {
        float4 a = xp[(size_t)r * HW4 + pos];
        m.x = fmaxf(m.x, a.x);
        m.y = fmaxf(m.y, a.y);
        m.z = fmaxf(m.z, a.z);
        m.w = fmaxf(m.w, a.w);
    }

    // red[rg][pos*4 .. pos*4+3] = m   (b128 write, conflict-free)
    ((float4*)red)[rg * HW4 + pos] = m;
    __syncthreads();

    if (t < HW) {
        float v = red[t];
#pragma unroll
        for (int g = 1; g < 16; ++g) v = fmaxf(v, red[g * HW + t]);
        pooled[((size_t)b * C_DIM + c) * HW + t] = v;
    }
}

// ---------------- Kernel 2: 1x1 conv + GeM, fused (unchanged) ----------------
// grid = 256 blocks: b = bx>>3, o-tile (32 wide) = bx&7.
// block = 128 threads: o_l = t&31, part = t>>5 (4 h-splits of 44 pos).
__global__ __launch_bounds__(128) void conv_gem_kernel(
    const float* __restrict__ pooled, const float* __restrict__ Wm,
    const float* __restrict__ p, float* __restrict__ out)
{
    int bx = blockIdx.x;
    int b  = bx >> 3;
    int ot = bx & 7;
    int t  = threadIdx.x;
    int o_l  = t & 31;
    int part = t >> 5;
    int o = ot * 32 + o_l;

    __shared__ __align__(16) float pl[32 * HW];  // pooled c-tile [32][176]
    __shared__ float wl[32 * 33];                // W tile [c][o], padded

    float acc[44];
#pragma unroll
    for (int j = 0; j < 44; ++j) acc[j] = 0.f;

    for (int c0 = 0; c0 < C_DIM; c0 += 32) {
        __syncthreads();
        const float* src = pooled + ((size_t)b * C_DIM + c0) * HW;
        for (int i = t; i < 32 * HW; i += 128) pl[i] = src[i];
        for (int i = t; i < 32 * 32; i += 128) {
            int oo = i >> 5;
            int cc = i & 31;
            wl[cc * 33 + oo] = Wm[(size_t)(ot * 32 + oo) * C_DIM + c0 + cc];
        }
        __syncthreads();

        float wreg[32];
#pragma unroll
        for (int cc = 0; cc < 32; ++cc) wreg[cc] = wl[cc * 33 + o_l];

#pragma unroll 4
        for (int cc = 0; cc < 32; ++cc) {
            const float4* p4 = (const float4*)(pl + cc * HW + part * 44);
            float w = wreg[cc];
#pragma unroll
            for (int j = 0; j < 11; ++j) {
                float4 v = p4[j];
                acc[4 * j + 0] = fmaf(v.x, w, acc[4 * j + 0]);
                acc[4 * j + 1] = fmaf(v.y, w, acc[4 * j + 1]);
                acc[4 * j + 2] = fmaf(v.z, w, acc[4 * j + 2]);
                acc[4 * j + 3] = fmaf(v.w, w, acc[4 * j + 3]);
            }
        }
    }

    float pw = p[part];
    float s = 0.f;
#pragma unroll
    for (int j = 0; j < 44; ++j) {
        float v = fmaxf(acc[j], 1e-6f);
        s += __expf(pw * __logf(v));
    }
    float g = __powf(s * (1.0f / 44.0f), 1.0f / pw);
    out[((size_t)b * O_DIM + o) * 4 + part] = g;
}

extern "C" void kernel_launch(void* const* d_in, const int* in_sizes, int n_in,
                              void* d_out, int out_size, void* d_ws, size_t ws_size,
                              hipStream_t stream)
{
    const float* x    = (const float*)d_in[0];   // [1,128,4096,16,11] fp32
    const int*   seqL = (const int*)d_in[1];     // [32]
    const float* Wm   = (const float*)d_in[2];   // [256,128]
    const float* p    = (const float*)d_in[3];   // [4]
    float* out    = (float*)d_out;               // [32,256,4]
    float* pooled = (float*)d_ws;                // [32,128,176] = 2.88 MB

    seg_max_kernel<<<B_SEG * C_DIM, 704, 0, stream>>>(x, seqL, pooled);
    conv_gem_kernel<<<256, 128, 0, stream>>>(pooled, Wm, p, out);
}